// Round 7
// baseline (756.671 us; speedup 1.0000x reference)
//
#include <hip/hip_runtime.h>
#include <hip/hip_bf16.h>
#include <stdint.h>

#define BATCH 8
#define SEQ   4096
#define DM    512
#define HD    120

typedef __bf16   v8bf  __attribute__((ext_vector_type(8)));
typedef float    v16f  __attribute__((ext_vector_type(16)));
typedef int      i4    __attribute__((ext_vector_type(4)));
typedef uint32_t u32x2 __attribute__((ext_vector_type(2)));
typedef float    f32x4 __attribute__((ext_vector_type(4)));

static __device__ __forceinline__ ushort f2bf(float x) {
  uint32_t u = __builtin_bit_cast(uint32_t, x);
  return (ushort)((u + 0x7fffu + ((u >> 16) & 1u)) >> 16);
}

// async global->LDS, 16B/lane: LDS base wave-uniform (HW adds lane*16 to dest
// implicitly? NO - dest is base+lane*size); global src per-lane.
static __device__ __forceinline__ void gld16(const void* g, void* l) {
  __builtin_amdgcn_global_load_lds(
      (const __attribute__((address_space(1))) uint32_t*)g,
      (__attribute__((address_space(3))) uint32_t*)l, 16, 0, 0);
}

// -------------------------------------------------------------------------
// prep_kernel: 1024 blocks x 256 thr. Even blocks: ctx GEMM -> bf16 [B*S][128]
// pre-swizzled: 16B-slot s of row r stored at slot s ^ (r & 15). Odd blocks:
// compress 64 mask rows -> bits, TRANSPOSED layout bitsT[b][pw 0..127][q 0..4095]
// (LDS transpose so both read and write are coalesced).
// -------------------------------------------------------------------------
__global__ __launch_bounds__(256) void prep_kernel(
    const float* __restrict__ q, const float* __restrict__ wq,
    const float* __restrict__ bq, const float* __restrict__ wt,
    const int* __restrict__ mask, ushort* __restrict__ ctx,
    uint32_t* __restrict__ bitsT)
{
  __shared__ __align__(16) char smem[33024];
  const int t = threadIdx.x;

  if (blockIdx.x & 1) {
    // ---- mask compression, 64 rows ----
    uint32_t (*bw)[129] = (uint32_t(*)[129])smem;  // [64][129]
    const int cb = blockIdx.x >> 1;                // 0..511
    const size_t row0 = (size_t)cb * 64;
    const int b     = (int)(row0 >> 12);
    const int qbase = (int)(row0 & 4095);
    const int rhalf = t >> 7, pw = t & 127;
    for (int s = 0; s < 32; ++s) {
      int row = s * 2 + rhalf;
      const int* mp = mask + (row0 + row) * SEQ + pw * 32;
      uint32_t wd = 0;
      #pragma unroll
      for (int k = 0; k < 8; ++k) {
        i4 m = *(const i4*)(mp + k * 4);
        wd |= (uint32_t)(m.x != 0) << (k * 4);
        wd |= (uint32_t)(m.y != 0) << (k * 4 + 1);
        wd |= (uint32_t)(m.z != 0) << (k * 4 + 2);
        wd |= (uint32_t)(m.w != 0) << (k * 4 + 3);
      }
      bw[row][pw] = wd;
    }
    __syncthreads();
    const int qq = t & 63, pg = t >> 6;            // 4 pw-groups x 64 q
    uint32_t* bT = bitsT + (size_t)b * 128 * 4096 + qbase + qq;
    #pragma unroll 8
    for (int i = 0; i < 32; ++i) {
      int pw2 = pg * 32 + i;
      bT[(size_t)pw2 * 4096] = bw[qq][pw2];
    }
    return;
  }

  // ---- ctx GEMM, 64 rows ----
  float (*qs)[68]  = (float(*)[68])smem;           // 8.7 KB
  float (*ws2)[136] = (float(*)[136])(smem + 8704); // 17.4 KB
  const int gb = blockIdx.x >> 1;
  const int tx = t & 31, ty = t >> 5;
  const size_t row0 = (size_t)gb * 64;
  const int qr = t >> 2, qk = (t & 3) * 8;

  float acc[8][4];
  #pragma unroll
  for (int j = 0; j < 8; ++j)
    #pragma unroll
    for (int i = 0; i < 4; ++i) acc[j][i] = 0.f;

  for (int k0 = 0; k0 < DM; k0 += 32) {
    __syncthreads();
    {
      f32x4 v0 = *(const f32x4*)&q[(row0 + qr) * DM + k0 + qk];
      f32x4 v1 = *(const f32x4*)&q[(row0 + qr) * DM + k0 + qk + 4];
      #pragma unroll
      for (int i = 0; i < 4; ++i) qs[qk + i][qr] = v0[i];
      #pragma unroll
      for (int i = 0; i < 4; ++i) qs[qk + 4 + i][qr] = v1[i];
    }
    #pragma unroll
    for (int i = 0; i < 16; ++i) {
      int flat = t + i * 256;
      int kk = flat & 31, c = flat >> 5;
      ws2[kk][c] = (c < HD) ? wq[c * DM + k0 + kk] : 0.f;
    }
    __syncthreads();
    #pragma unroll
    for (int kk = 0; kk < 32; ++kk) {
      f32x4 bv = *(const f32x4*)&ws2[kk][tx * 4];
      f32x4 a0 = *(const f32x4*)&qs[kk][ty * 8];
      f32x4 a1 = *(const f32x4*)&qs[kk][ty * 8 + 4];
      #pragma unroll
      for (int r = 0; r < 4; ++r)
        #pragma unroll
        for (int c = 0; c < 4; ++c) {
          acc[r][c]     = fmaf(a0[r], bv[c], acc[r][c]);
          acc[4 + r][c] = fmaf(a1[r], bv[c], acc[4 + r][c]);
        }
    }
  }

  float wtv[4], bqv[4];
  #pragma unroll
  for (int i = 0; i < 4; ++i) {
    int c = tx * 4 + i;
    wtv[i] = (c < HD) ? wt[c] : 0.f;
    bqv[i] = (c < HD) ? bq[c] : 0.f;
  }
  #pragma unroll
  for (int j = 0; j < 8; ++j) {
    int rloc = ty * 8 + j;
    float v[4]; float ss = 0.f;
    #pragma unroll
    for (int i = 0; i < 4; ++i) {
      v[i] = (acc[j][i] + bqv[i]) * wtv[i];
      ss = fmaf(v[i], v[i], ss);
    }
    #pragma unroll
    for (int xm = 1; xm < 32; xm <<= 1) ss += __shfl_xor(ss, xm, 64);
    float rinv = 1.f / fmaxf(sqrtf(ss), 1e-12f);
    uint32_t p0 = (uint32_t)f2bf(v[0] * rinv) | ((uint32_t)f2bf(v[1] * rinv) << 16);
    uint32_t p1 = (uint32_t)f2bf(v[2] * rinv) | ((uint32_t)f2bf(v[3] * rinv) << 16);
    u32x2 o = {p0, p1};
    char* dst = (char*)ctx + (row0 + rloc) * 256 +
                (((tx >> 1) ^ (rloc & 15)) << 4) + (tx & 1) * 8;
    *(u32x2*)dst = o;
  }
}

// -------------------------------------------------------------------------
// attn_kernel: 512 blocks x 4 waves, NO barriers in main loops. Block = 64
// q-rows; wave = p-quarter (1024 cols). Wave-private LDS ring (2 x 8KB) staged
// via global_load_lds from pre-swizzled ctx; sync = counted vmcnt(10) only.
// Wave tile 32p x 64q: each A-frag ds_read feeds 2 MFMAs (qf[0], qf[1]
// persistent). D[p][q] 32x32x16: lane = one q-col, mask bits = 1 coalesced
// u32 per qblk per tile from transposed bitsT. Fixed softmax max = 1.0.
// -------------------------------------------------------------------------
#define MFMA32(A, B, C) __builtin_amdgcn_mfma_f32_32x32x16_bf16(A, B, C, 0, 0, 0)
#define Z16 (v16f){0.f,0.f,0.f,0.f,0.f,0.f,0.f,0.f,0.f,0.f,0.f,0.f,0.f,0.f,0.f,0.f}

#define STAGE(bufsel, j) do {                                                 \
  const char* _g = ctxb + (size_t)(P0 + (j) * 32) * 256 + lane * 16;          \
  char* _d = wbase + (bufsel) * 8192;                                         \
  gld16(_g,        _d);        gld16(_g + 1024, _d + 1024);                   \
  gld16(_g + 2048, _d + 2048); gld16(_g + 3072, _d + 3072);                   \
  gld16(_g + 4096, _d + 4096); gld16(_g + 5120, _d + 5120);                   \
  gld16(_g + 6144, _d + 6144); gld16(_g + 7168, _d + 7168);                   \
} while (0)

#define TILE_COMPUTE(j)                                                       \
  asm volatile("s_waitcnt vmcnt(10)" ::: "memory");                           \
  __builtin_amdgcn_sched_barrier(0);                                          \
  v8bf fr[8];                                                                 \
  {                                                                           \
    const char* _fb = wbase + ((j) & 1) * 8192 + q5 * 256;                    \
    _Pragma("unroll")                                                         \
    for (int _c = 0; _c < 8; ++_c)                                            \
      fr[_c] = *(const v8bf*)(_fb + (((_c * 2 + hi) ^ (lane & 15)) << 4));    \
  }                                                                           \
  asm volatile("s_waitcnt lgkmcnt(0)" ::: "memory");                          \
  __builtin_amdgcn_sched_barrier(0);                                          \
  int jn = ((j) + 2 < 32) ? (j) + 2 : 31;                                     \
  STAGE((j) & 1, jn);                                                         \
  v16f a0 = Z16, a1 = Z16;                                                    \
  _Pragma("unroll")                                                           \
  for (int _c = 0; _c < 8; ++_c) {                                            \
    a0 = MFMA32(fr[_c], qf[0][_c], a0);                                       \
    a1 = MFMA32(fr[_c], qf[1][_c], a1);                                       \
  }

__global__ __launch_bounds__(256) void attn_kernel(
    const ushort* __restrict__ ctx, const uint32_t* __restrict__ bitsT,
    float* __restrict__ out)
{
  __shared__ __align__(16) char lds[66816];
  float* lW   = (float*)(lds + 65536);        // [4][64]
  float* lfin = (float*)(lds + 66560);        // [64]

  const int t    = threadIdx.x;
  const int b    = blockIdx.x & 7;            // batch -> XCD-pinned panel
  const int qg   = blockIdx.x >> 3;           // 0..63
  const int w    = t >> 6, lane = t & 63;
  const int q5   = lane & 31, hi = lane >> 5;
  const int q0   = qg * 64;
  const int P0   = w * 1024;                  // wave's p-quarter
  const char* ctxb = (const char*)ctx + (size_t)b * SEQ * 256;
  char* wbase = lds + w * 16384;

  // persistent Q fragments (B-operand), 2 q-blocks x 8 K-chunks
  v8bf qf[2][8];
  #pragma unroll
  for (int qb = 0; qb < 2; ++qb) {
    int row = q0 + qb * 32 + q5;
    #pragma unroll
    for (int c = 0; c < 8; ++c)
      qf[qb][c] = *(const v8bf*)(ctxb + (size_t)row * 256 +
                                 (((c * 2 + hi) ^ (row & 15)) << 4));
  }

  const uint32_t* btp = bitsT + ((size_t)b * 128 + (P0 >> 5)) * 4096 + q0 + q5;
  float* obase = out + ((size_t)b * SEQ + q0 + q5) * SEQ + P0 + hi * 4;

  float lsum0 = 0.f, lsum1 = 0.f;
  uint32_t bc0, bc1, bn0, bn1;

  // ================= PASS A: masked sum of exp(s-1) =================
  STAGE(0, 0);
  bc0 = btp[0]; bc1 = btp[32];
  STAGE(1, 1);
  bn0 = btp[4096]; bn1 = btp[4096 + 32];

  for (int j = 0; j < 32; ++j) {
    TILE_COMPUTE(j)
    #pragma unroll
    for (int r = 0; r < 16; ++r) {
      int bit = (r >> 2) * 8 + hi * 4 + (r & 3);
      float e0 = __expf(a0[r] - 1.0f);
      float e1 = __expf(a1[r] - 1.0f);
      lsum0 += ((bc0 >> bit) & 1u) ? e0 : 0.f;
      lsum1 += ((bc1 >> bit) & 1u) ? e1 : 0.f;
    }
    bc0 = bn0; bc1 = bn1;
    bn0 = btp[(size_t)jn * 4096];
    bn1 = btp[(size_t)jn * 4096 + 32];
  }

  // ================= merge l across hi-halves + 4 p-waves =================
  lsum0 += __shfl_xor(lsum0, 32, 64);
  lsum1 += __shfl_xor(lsum1, 32, 64);
  if (hi == 0) {
    lW[w * 64 + q5]      = lsum0;
    lW[w * 64 + 32 + q5] = lsum1;
  }
  __syncthreads();
  if (t < 64) {
    float lf = lW[t] + lW[64 + t] + lW[128 + t] + lW[192 + t];
    lfin[t] = (lf > 0.f) ? (1.f / lf) : 0.f;
  }
  __syncthreads();
  const float lir0 = lfin[q5];
  const float lir1 = lfin[32 + q5];

  // ================= PASS B: recompute, scale, write =================
  STAGE(0, 0);
  bc0 = btp[0]; bc1 = btp[32];
  STAGE(1, 1);
  bn0 = btp[4096]; bn1 = btp[4096 + 32];

  for (int j = 0; j < 32; ++j) {
    TILE_COMPUTE(j)
    #pragma unroll
    for (int rr = 0; rr < 4; ++rr) {
      f32x4 o0, o1;
      #pragma unroll
      for (int i = 0; i < 4; ++i) {
        int bit = rr * 8 + hi * 4 + i;
        o0[i] = ((bc0 >> bit) & 1u) ? __expf(a0[rr * 4 + i] - 1.0f) * lir0 : 0.f;
        o1[i] = ((bc1 >> bit) & 1u) ? __expf(a1[rr * 4 + i] - 1.0f) * lir1 : 0.f;
      }
      __builtin_nontemporal_store(o0, (f32x4*)(obase + (size_t)j * 32 + rr * 8));
      __builtin_nontemporal_store(o1, (f32x4*)(obase + (size_t)32 * SEQ +
                                               (size_t)j * 32 + rr * 8));
    }
    bc0 = bn0; bc1 = bn1;
    bn0 = btp[(size_t)jn * 4096];
    bn1 = btp[(size_t)jn * 4096 + 32];
  }
}

// -------------------------------------------------------------------------
extern "C" void kernel_launch(void* const* d_in, const int* in_sizes, int n_in,
                              void* d_out, int out_size, void* d_ws, size_t ws_size,
                              hipStream_t stream) {
  const float* query = (const float*)d_in[0];
  const int*   mask  = (const int*)d_in[1];
  const float* w_q   = (const float*)d_in[2];
  const float* b_q   = (const float*)d_in[3];
  const float* wt    = (const float*)d_in[4];
  float* out = (float*)d_out;

  ushort*   ctx   = (ushort*)d_ws;                             // 8 MB
  uint32_t* bitsT = (uint32_t*)((char*)d_ws + (16u << 20));    // +16 MB

  prep_kernel<<<dim3(1024), dim3(256), 0, stream>>>(query, w_q, b_q, wt, mask, ctx, bitsT);
  attn_kernel<<<dim3(512), dim3(256), 0, stream>>>(ctx, bitsT, out);
}

// Round 8
// 394.429 us; speedup vs baseline: 1.9184x; 1.9184x over previous
//
#include <hip/hip_runtime.h>
#include <hip/hip_bf16.h>
#include <stdint.h>

#define BATCH 8
#define SEQ   4096
#define DM    512
#define HD    120
#define PH    2048   // p-range per attn block
#define NT    32     // tiles per pass (PH/64)

typedef __bf16   v8bf  __attribute__((ext_vector_type(8)));
typedef float    v4f   __attribute__((ext_vector_type(4)));
typedef int      i4    __attribute__((ext_vector_type(4)));
typedef uint32_t u32x2 __attribute__((ext_vector_type(2)));
typedef uint32_t u32x4 __attribute__((ext_vector_type(4)));
typedef float    f32x4 __attribute__((ext_vector_type(4)));

static __device__ __forceinline__ ushort f2bf(float x) {
  uint32_t u = __builtin_bit_cast(uint32_t, x);
  return (ushort)((u + 0x7fffu + ((u >> 16) & 1u)) >> 16);
}

// -------------------------------------------------------------------------
// prep_kernel: 1024 blocks x 256 thr. Even blocks: ctx GEMM -> bf16
// [B*S][128] PRE-SWIZZLED (byte-in-row = slot*16 ^ ((row&7)<<4)). Odd
// blocks: compress 64 mask rows -> bitsT[b][pw 0..127][q 0..4095]
// (transposed via LDS so attn bit-reads are coalesced).
// -------------------------------------------------------------------------
__global__ __launch_bounds__(256) void prep_kernel(
    const float* __restrict__ q, const float* __restrict__ wq,
    const float* __restrict__ bq, const float* __restrict__ wt,
    const int* __restrict__ mask, ushort* __restrict__ ctx,
    uint32_t* __restrict__ bitsT)
{
  __shared__ __align__(16) char smem[33024];
  const int t = threadIdx.x;

  if (blockIdx.x & 1) {
    // ---- mask compression, 64 rows, transposed output ----
    uint32_t (*bw)[129] = (uint32_t(*)[129])smem;  // [64][129]
    const int cb = blockIdx.x >> 1;                // 0..511
    const size_t row0 = (size_t)cb * 64;
    const int b     = (int)(row0 >> 12);
    const int qbase = (int)(row0 & 4095);
    const int rhalf = t >> 7, pw = t & 127;
    for (int s = 0; s < 32; ++s) {
      int row = s * 2 + rhalf;
      const int* mp = mask + (row0 + row) * SEQ + pw * 32;
      uint32_t wd = 0;
      #pragma unroll
      for (int k = 0; k < 8; ++k) {
        i4 m = *(const i4*)(mp + k * 4);
        wd |= (uint32_t)(m.x != 0) << (k * 4);
        wd |= (uint32_t)(m.y != 0) << (k * 4 + 1);
        wd |= (uint32_t)(m.z != 0) << (k * 4 + 2);
        wd |= (uint32_t)(m.w != 0) << (k * 4 + 3);
      }
      bw[row][pw] = wd;
    }
    __syncthreads();
    const int qq = t & 63, pg = t >> 6;            // 4 pw-groups x 64 q
    uint32_t* bT = bitsT + (size_t)b * 128 * 4096 + qbase + qq;
    #pragma unroll 8
    for (int i = 0; i < 32; ++i) {
      int pw2 = pg * 32 + i;
      bT[(size_t)pw2 * 4096] = bw[qq][pw2];
    }
    return;
  }

  // ---- ctx GEMM, 64 rows ----
  float (*qs)[68]   = (float(*)[68])smem;
  float (*ws2)[136] = (float(*)[136])(smem + 8704);
  const int gb = blockIdx.x >> 1;                  // 0..511
  const int tx = t & 31, ty = t >> 5;
  const size_t row0 = (size_t)gb * 64;
  const int qr = t >> 2, qk = (t & 3) * 8;

  float acc[8][4];
  #pragma unroll
  for (int j = 0; j < 8; ++j)
    #pragma unroll
    for (int i = 0; i < 4; ++i) acc[j][i] = 0.f;

  for (int k0 = 0; k0 < DM; k0 += 32) {
    __syncthreads();
    {
      f32x4 v0 = *(const f32x4*)&q[(row0 + qr) * DM + k0 + qk];
      f32x4 v1 = *(const f32x4*)&q[(row0 + qr) * DM + k0 + qk + 4];
      #pragma unroll
      for (int i = 0; i < 4; ++i) qs[qk + i][qr] = v0[i];
      #pragma unroll
      for (int i = 0; i < 4; ++i) qs[qk + 4 + i][qr] = v1[i];
    }
    #pragma unroll
    for (int i = 0; i < 16; ++i) {
      int flat = t + i * 256;
      int kk = flat & 31, c = flat >> 5;
      ws2[kk][c] = (c < HD) ? wq[c * DM + k0 + kk] : 0.f;
    }
    __syncthreads();
    #pragma unroll
    for (int kk = 0; kk < 32; ++kk) {
      f32x4 bv = *(const f32x4*)&ws2[kk][tx * 4];
      f32x4 a0 = *(const f32x4*)&qs[kk][ty * 8];
      f32x4 a1 = *(const f32x4*)&qs[kk][ty * 8 + 4];
      #pragma unroll
      for (int r = 0; r < 4; ++r)
        #pragma unroll
        for (int c = 0; c < 4; ++c) {
          acc[r][c]     = fmaf(a0[r], bv[c], acc[r][c]);
          acc[4 + r][c] = fmaf(a1[r], bv[c], acc[4 + r][c]);
        }
    }
  }

  float wtv[4], bqv[4];
  #pragma unroll
  for (int i = 0; i < 4; ++i) {
    int c = tx * 4 + i;
    wtv[i] = (c < HD) ? wt[c] : 0.f;
    bqv[i] = (c < HD) ? bq[c] : 0.f;
  }
  #pragma unroll
  for (int j = 0; j < 8; ++j) {
    int r = ty * 8 + j;
    float v[4]; float ss = 0.f;
    #pragma unroll
    for (int i = 0; i < 4; ++i) {
      v[i] = (acc[j][i] + bqv[i]) * wtv[i];
      ss = fmaf(v[i], v[i], ss);
    }
    #pragma unroll
    for (int xm = 1; xm < 32; xm <<= 1) ss += __shfl_xor(ss, xm, 64);
    float rinv = 1.f / fmaxf(sqrtf(ss), 1e-12f);
    uint32_t p0 = (uint32_t)f2bf(v[0] * rinv) | ((uint32_t)f2bf(v[1] * rinv) << 16);
    uint32_t p1 = (uint32_t)f2bf(v[2] * rinv) | ((uint32_t)f2bf(v[3] * rinv) << 16);
    u32x2 o = {p0, p1};
    char* dst = (char*)ctx + (row0 + r) * 256 +
                (((tx >> 1) * 16) ^ ((r & 7) << 4)) + (tx & 1) * 8;
    *(u32x2*)dst = o;
  }
}

// -------------------------------------------------------------------------
// attn: R5 pipeline, p-split into two kernels for 2x grid parallelism.
// Block = 64 q-rows x 2048 p (1024 blocks, 4 blocks/CU). 4 waves share a
// double-buffered 64-p-row LDS tile, REG-STAGED (global->reg->ds_write);
// BAR = lgkmcnt(0) + s_barrier only (no vmcnt(0) in loop). 16x16x32 MFMA
// transposed D[p][q]: lane = q-row (ln), p contiguous per acc. Fixed
// softmax max = 1.0. A: l-partials to ws; B: scale + plain f32x4 stores.
// -------------------------------------------------------------------------
#define MFMA(A, B, C) __builtin_amdgcn_mfma_f32_16x16x32_bf16(A, B, C, 0, 0, 0)

static __device__ __forceinline__ v8bf ldfrag(const char* base, int row, int slot) {
  int byte = row * 256 + ((slot * 16) ^ ((row & 7) << 4));
  return __builtin_bit_cast(v8bf, *(const u32x4*)(base + byte));
}

#define STG_LOAD(R, j) do {                                                   \
  const char* _g = ctxb + (size_t)(P0 + (j) * 64) * 256 + w * 4096 + lane * 16;\
  R##0 = *(const u32x4*)(_g);        R##1 = *(const u32x4*)(_g + 1024);       \
  R##2 = *(const u32x4*)(_g + 2048); R##3 = *(const u32x4*)(_g + 3072);       \
} while (0)

#define STG_WRITE(R, buf) do {                                                \
  char* _l = (buf) + w * 4096 + lane * 16;                                    \
  *(u32x4*)(_l)        = R##0;  *(u32x4*)(_l + 1024) = R##1;                  \
  *(u32x4*)(_l + 2048) = R##2;  *(u32x4*)(_l + 3072) = R##3;                  \
} while (0)

#define QKT(buf, acc) do {                                                    \
  _Pragma("unroll")                                                           \
  for (int _t = 0; _t < 4; ++_t) {                                            \
    acc[_t] = (v4f){0.f, 0.f, 0.f, 0.f};                                      \
    _Pragma("unroll")                                                         \
    for (int _k = 0; _k < 4; ++_k) {                                          \
      v8bf _a = ldfrag(buf, _t * 16 + ln, _k * 4 + g);                        \
      acc[_t] = MFMA(_a, qf[_k], acc[_t]);                                    \
    }                                                                         \
  }                                                                           \
} while (0)

#define LDB(x, y, tj) do {                                                    \
  x = btb[(size_t)(tj) * 2 * 4096];                                           \
  y = btb[((size_t)(tj) * 2 + 1) * 4096];                                     \
} while (0)

#define EPIA() do {                                                           \
  _Pragma("unroll")                                                           \
  for (int _t2 = 0; _t2 < 4; ++_t2) {                                         \
    uint32_t nib = ((_t2 < 2 ? bcx : bcy) >> ((_t2 & 1) * 16 + g * 4));       \
    _Pragma("unroll")                                                         \
    for (int _i = 0; _i < 4; ++_i) {                                          \
      float e = __expf(acc[_t2][_i] - 1.0f);                                  \
      lsum += ((nib >> _i) & 1u) ? e : 0.f;                                   \
    }                                                                         \
  }                                                                           \
} while (0)

#define EPIB(tj) do {                                                         \
  _Pragma("unroll")                                                           \
  for (int _t2 = 0; _t2 < 4; ++_t2) {                                         \
    uint32_t nib = ((_t2 < 2 ? bcx : bcy) >> ((_t2 & 1) * 16 + g * 4));       \
    f32x4 o;                                                                  \
    _Pragma("unroll")                                                         \
    for (int _i = 0; _i < 4; ++_i)                                            \
      o[_i] = ((nib >> _i) & 1u) ? __expf(acc[_t2][_i] - 1.0f) * lir : 0.f;   \
    *(f32x4*)(orow + (size_t)(tj) * 64 + _t2 * 16 + g * 4) = o;               \
  }                                                                           \
} while (0)

#define BAR() do {                                                            \
  asm volatile("s_waitcnt lgkmcnt(0)" ::: "memory");                          \
  __builtin_amdgcn_s_barrier();                                               \
  __builtin_amdgcn_sched_barrier(0);                                          \
} while (0)

#define ATTN_COMMON                                                           \
  __shared__ __align__(16) char lds[32768];                                   \
  char* B0 = lds;                                                             \
  char* B1 = lds + 16384;                                                     \
  const int t    = threadIdx.x;                                               \
  const int b    = blockIdx.x & 7;                                            \
  const int rest = blockIdx.x >> 3;                                           \
  const int ph   = rest & 1;                                                  \
  const int qg   = rest >> 1;                                                 \
  const int w    = t >> 6, lane = t & 63;                                     \
  const int ln   = lane & 15, g = lane >> 4;                                  \
  const int q0   = qg * 64;                                                   \
  const int P0   = ph * PH;                                                   \
  const int qrow = q0 + w * 16 + ln;                                          \
  const char* ctxb = (const char*)ctx + (size_t)b * SEQ * 256;                \
  const uint32_t* __restrict__ btb =                                          \
      bitsT + ((size_t)b * 128 + (P0 >> 5)) * 4096 + qrow;                    \
  v8bf qf[4];                                                                 \
  _Pragma("unroll")                                                           \
  for (int kk = 0; kk < 4; ++kk) {                                            \
    int slot = kk * 4 + g;                                                    \
    qf[kk] = *(const v8bf*)(ctxb + (size_t)qrow * 256 +                       \
                            ((slot * 16) ^ ((qrow & 7) << 4)));               \
  }                                                                           \
  u32x4 sA0, sA1, sA2, sA3, sB0, sB1, sB2, sB3;                               \
  uint32_t bcx, bcy, bnx = 0, bny = 0;

__global__ __launch_bounds__(256) void attnA_kernel(
    const ushort* __restrict__ ctx, const uint32_t* __restrict__ bitsT,
    float* __restrict__ lpart)
{
  ATTN_COMMON
  float lsum = 0.f;

  STG_LOAD(sA, 0);
  STG_WRITE(sA, B0);
  STG_LOAD(sB, 1);
  LDB(bcx, bcy, 0);
  __syncthreads();

  for (int jj = 0; jj < NT; jj += 2) {
    if (jj + 1 < NT) LDB(bnx, bny, jj + 1);
    if (jj + 2 < NT) STG_LOAD(sA, jj + 2);
    { v4f acc[4]; QKT(B0, acc); STG_WRITE(sB, B1); EPIA(); }
    BAR();
    bcx = bnx; bcy = bny;

    if (jj + 2 < NT) LDB(bnx, bny, jj + 2);
    if (jj + 3 < NT) STG_LOAD(sB, jj + 3);
    { v4f acc[4]; QKT(B1, acc); if (jj + 2 < NT) STG_WRITE(sA, B0); EPIA(); }
    BAR();
    bcx = bnx; bcy = bny;
  }

  // reduce over the 4 g-groups (same qrow), then one store per row
  lsum += __shfl_xor(lsum, 16, 64);
  lsum += __shfl_xor(lsum, 32, 64);
  if (g == 0)
    lpart[(size_t)ph * (BATCH * SEQ) + (size_t)b * SEQ + qrow] = lsum;
}

__global__ __launch_bounds__(256) void attnB_kernel(
    const ushort* __restrict__ ctx, const uint32_t* __restrict__ bitsT,
    const float* __restrict__ lpart, float* __restrict__ out)
{
  ATTN_COMMON
  const size_t grow = (size_t)b * SEQ + qrow;
  const float lf = lpart[grow] + lpart[(size_t)(BATCH * SEQ) + grow];
  const float lir = (lf > 0.f) ? (1.f / lf) : 0.f;
  float* __restrict__ orow = out + grow * SEQ + P0;

  STG_LOAD(sA, 0);
  STG_WRITE(sA, B0);
  STG_LOAD(sB, 1);
  LDB(bcx, bcy, 0);
  __syncthreads();

  for (int jj = 0; jj < NT; jj += 2) {
    if (jj + 1 < NT) LDB(bnx, bny, jj + 1);
    if (jj + 2 < NT) STG_LOAD(sA, jj + 2);
    { v4f acc[4]; QKT(B0, acc); STG_WRITE(sB, B1); EPIB(jj); }
    BAR();
    bcx = bnx; bcy = bny;

    if (jj + 2 < NT) LDB(bnx, bny, jj + 2);
    if (jj + 3 < NT) STG_LOAD(sB, jj + 3);
    { v4f acc[4]; QKT(B1, acc); if (jj + 2 < NT) STG_WRITE(sA, B0); EPIB(jj + 1); }
    BAR();
    bcx = bnx; bcy = bny;
  }
}

// -------------------------------------------------------------------------
extern "C" void kernel_launch(void* const* d_in, const int* in_sizes, int n_in,
                              void* d_out, int out_size, void* d_ws, size_t ws_size,
                              hipStream_t stream) {
  const float* query = (const float*)d_in[0];
  const int*   mask  = (const int*)d_in[1];
  const float* w_q   = (const float*)d_in[2];
  const float* b_q   = (const float*)d_in[3];
  const float* wt    = (const float*)d_in[4];
  float* out = (float*)d_out;

  ushort*   ctx   = (ushort*)d_ws;                               // 8.39 MB @0
  uint32_t* bitsT = (uint32_t*)((char*)d_ws + (9u << 20));       // 16.78 MB @9M
  float*    lpart = (float*)((char*)d_ws + (26u << 20));         // 256 KB @26M

  prep_kernel <<<dim3(1024), dim3(256), 0, stream>>>(query, w_q, b_q, wt, mask, ctx, bitsT);
  attnA_kernel<<<dim3(1024), dim3(256), 0, stream>>>(ctx, bitsT, lpart);
  attnB_kernel<<<dim3(1024), dim3(256), 0, stream>>>(ctx, bitsT, lpart, out);
}